// Round 8
// baseline (102.328 us; speedup 1.0000x reference)
//
#include <hip/hip_runtime.h>

// Problem constants
#define BB   8
#define CC   128
#define CR   16      // reduced channels = 128/8
#define HH   128
#define WW   128
#define HWSZ 16384   // 128*128
#define K2   9
#define NFRAG 72     // 8 ctiles * 9 taps

typedef _Float16 f16x8 __attribute__((ext_vector_type(8)));
typedef float    f32x4 __attribute__((ext_vector_type(4)));

// ws layout (float slots):
//   t     : [0, 2097152)             (b, cr, h, w) fp32
//   part  : [2097152, +16384)
//   stats : [2113536, +256)          (b,cr) x {scale,shift}
//   tn16  : [2113792, +1048576)      normalized t, f16, (b, hw, 16) packed
//   afrag : [3162368, +18432)        A fragments f16x8/lane (bias folded at kk=16)
#define WS_T     0
#define WS_PART  2097152
#define WS_STATS 2113536
#define WS_TN16  2113792
#define WS_AFRAG 3162368

__global__ __launch_bounds__(256) void k_conv1(const float* __restrict__ x,
                                               const float* __restrict__ w1,
                                               float* __restrict__ t,
                                               float* __restrict__ part) {
    const int tile = blockIdx.x;   // 0..63
    const int b    = blockIdx.y;   // 0..7
    const int tid  = threadIdx.x;
    const int pix  = tile * 256 + tid;

    __shared__ float w1s[CR * CC];   // 8 KB
    for (int i = tid; i < CR * CC; i += 256) w1s[i] = w1[i];
    __syncthreads();

    const float* xb = x + (size_t)b * CC * HWSZ + pix;
    float acc[CR];
#pragma unroll
    for (int o = 0; o < CR; ++o) acc[o] = 0.f;

    for (int cin = 0; cin < CC; ++cin) {
        float xv = xb[(size_t)cin * HWSZ];
#pragma unroll
        for (int o = 0; o < CR; ++o)
            acc[o] = fmaf(w1s[o * CC + cin], xv, acc[o]);
    }

    float* tb = t + (size_t)b * CR * HWSZ + pix;
#pragma unroll
    for (int o = 0; o < CR; ++o) tb[(size_t)o * HWSZ] = acc[o];

    __shared__ float red[4][CR][2];
    const int lane = tid & 63;
    const int wv   = tid >> 6;
#pragma unroll
    for (int o = 0; o < CR; ++o) {
        float s = acc[o];
        float q = s * s;
#pragma unroll
        for (int off = 32; off > 0; off >>= 1) {
            s += __shfl_down(s, off, 64);
            q += __shfl_down(q, off, 64);
        }
        if (lane == 0) { red[wv][o][0] = s; red[wv][o][1] = q; }
    }
    __syncthreads();
    if (tid < CR) {
        const int o = tid;
        float s = red[0][o][0] + red[1][o][0] + red[2][o][0] + red[3][o][0];
        float q = red[0][o][1] + red[1][o][1] + red[2][o][1] + red[3][o][1];
        const int blk = b * 64 + tile;
        part[blk * 32 + o * 2 + 0] = s;
        part[blk * 32 + o * 2 + 1] = q;
    }
}

// grid = 128 blocks (b*16+o), block = 64; wave-reduce over 64 tiles
__global__ void k_stats(const float* __restrict__ part,
                        const float* __restrict__ gamma,
                        const float* __restrict__ beta,
                        float* __restrict__ stats) {
    const int b   = blockIdx.x >> 4;
    const int o   = blockIdx.x & 15;
    const int tle = threadIdx.x;            // 0..63
    float s = part[(b * 64 + tle) * 32 + o * 2 + 0];
    float q = part[(b * 64 + tle) * 32 + o * 2 + 1];
#pragma unroll
    for (int off = 32; off > 0; off >>= 1) {
        s += __shfl_down(s, off, 64);
        q += __shfl_down(q, off, 64);
    }
    if (tle == 0) {
        const float mean = s * (1.f / (float)HWSZ);
        const float var  = q * (1.f / (float)HWSZ) - mean * mean;
        const float rstd = rsqrtf(var + 1e-5f);
        const float sc   = gamma[o] * rstd;
        const float sh   = beta[o] - mean * sc;
        stats[(b * CR + o) * 2 + 0] = sc;
        stats[(b * CR + o) * 2 + 1] = sh;
    }
}

// Normalize t -> packed f16 (b, hw, 16); one thread per pixel.
__global__ __launch_bounds__(256) void k_norm(const float* __restrict__ ws_t,
                                              const float* __restrict__ stats,
                                              f16x8* __restrict__ tn16) {
    const int p  = blockIdx.x * 256 + threadIdx.x;   // 0..131071
    const int b  = p >> 14;
    const int pp = p & 16383;
    const float* tb = ws_t + (size_t)b * CR * HWSZ + pp;
    const float* st = stats + b * CR * 2;
    f16x8 lo, hi;
#pragma unroll
    for (int i = 0; i < 8; ++i) {
        float v0 = fmaf(tb[(size_t)i * HWSZ],       st[i * 2],       st[i * 2 + 1]);
        float v1 = fmaf(tb[(size_t)(i + 8) * HWSZ], st[(i + 8) * 2], st[(i + 8) * 2 + 1]);
        lo[i] = (_Float16)(v0 > 0.f ? v0 : 0.f);
        hi[i] = (_Float16)(v1 > 0.f ? v1 : 0.f);
    }
    tn16[(size_t)p * 2 + 0] = lo;
    tn16[(size_t)p * 2 + 1] = hi;
}

// Pre-swizzle w2 into MFMA A-fragments (f16), bias folded at kk==16.
// A-frag (16x16x32_f16): lane holds A[row=lane&15][kk=8*(lane>>4)+i].
__global__ __launch_bounds__(256) void k_prep(const float* __restrict__ w2,
                                              const float* __restrict__ b2,
                                              float* __restrict__ ws) {
    const int id = blockIdx.x * 256 + threadIdx.x;
    if (id >= NFRAG * 64) return;
    const int lane = id & 63;
    const int frag = id >> 6;           // ct*9 + k
    const int ct = frag / 9, k = frag - ct * 9;
    const int row = lane & 15, lg = lane >> 4;
    f16x8 v;
#pragma unroll
    for (int i = 0; i < 8; ++i) {
        const int kk = lg * 8 + i;
        float w = 0.f;
        if (kk < CR)        w = w2[(size_t)((ct * 16 + row) * K2 + k) * CR + kk];
        else if (kk == CR)  w = b2[(ct * 16 + row) * K2 + k];
        v[i] = (_Float16)w;
    }
    f16x8* dst = (f16x8*)(ws + WS_AFRAG);
    dst[frag * 64 + lane] = v;
}

// Fused MFMA weight-gen + dilated 3x3 involution apply.
// Block: 4 waves x 16 px (64 px of ONE row) x 32 channels (2 ctiles,
// processed as an unroll-1 loop to keep VGPR low -> 8 waves/SIMD).
// Interior fast path: 4 hoisted plane pointers, taps = compile-time
// immediate offsets (zero per-tap address VALU).
// 1D grid 8192, XCD-chunked swizzle, y innermost for L2 tap locality.
__global__ __launch_bounds__(256) void k_main(const float* __restrict__ x,
                                              const float* __restrict__ ws,
                                              float* __restrict__ out) {
    __shared__ f16x8 afl[18 * 64];   // 18432 B

    const int bid = blockIdx.x;
    const int w   = (bid & 7) * 1024 + (bid >> 3);
    const int y     = w & 127;
    const int xhalf = (w >> 7) & 1;
    const int z     = (w >> 8) & 3;
    const int b     = w >> 10;

    const int tid  = threadIdx.x;
    const int wv   = tid >> 6;
    const int lane = tid & 63;
    const int lg   = lane >> 4;           // 0..3
    const int ln   = lane & 15;
    const int colb = xhalf * 64 + wv * 16;
    const int col  = colb + ln;

    // ---- stage 18 A-frags into LDS ----
    {
        const float4* asrc = (const float4*)(ws + WS_AFRAG) + (size_t)z * 18 * 64;
        float4* adst = (float4*)afl;
        for (int i = tid; i < 18 * 64; i += 256) adst[i] = asrc[i];
    }

    // B-fragment: one 16B load of packed normalized t (bias lane kk==16 -> 1)
    const f16x8* tns = (const f16x8*)(ws + WS_TN16);
    f16x8 tnf = {};
    if (lg < 2) {
        tnf = tns[((size_t)(b << 14) + (size_t)y * WW + col) * 2 + lg];
    } else if (lg == 2) {
        tnf[0] = (_Float16)1.f;
    }

    const bool yint  = (y >= 2) && (y < HH - 2);
    const bool xint  = (colb >= 2) && (colb + 17 < WW);
    const bool allin = xint && yint;

    __syncthreads();

    const float* xb = x   + (size_t)b * CC * HWSZ;
    float*       ob = out + (size_t)b * CC * HWSZ;
    const int crow = lg * 4;
    const int pix  = y * WW + col;
    const f32x4 zc = {0.f, 0.f, 0.f, 0.f};

    if (allin) {
#pragma unroll 1
        for (int cti = 0; cti < 2; ++cti) {
            const int cb = z * 32 + cti * 16 + crow;
            const float* q0 = xb + (size_t)cb * HWSZ + pix;
            const float* q1 = q0 + HWSZ;
            const float* q2 = q0 + 2 * HWSZ;
            const float* q3 = q0 + 3 * HWSZ;
            f32x4 acc = {0.f, 0.f, 0.f, 0.f};
#pragma unroll
            for (int k = 0; k < K2; ++k) {
                const int d = ((k / 3) * 2 - 2) * WW + ((k % 3) * 2 - 2);  // compile-time
                const f16x8 af = afl[(cti * K2 + k) * 64 + lane];
                const f32x4 wg = __builtin_amdgcn_mfma_f32_16x16x32_f16(af, tnf, zc, 0, 0, 0);
                acc[0] = fmaf(wg[0], q0[d], acc[0]);
                acc[1] = fmaf(wg[1], q1[d], acc[1]);
                acc[2] = fmaf(wg[2], q2[d], acc[2]);
                acc[3] = fmaf(wg[3], q3[d], acc[3]);
            }
            float* o = ob + (size_t)cb * HWSZ + pix;
            o[0 * HWSZ] = acc[0];
            o[1 * HWSZ] = acc[1];
            o[2 * HWSZ] = acc[2];
            o[3 * HWSZ] = acc[3];
        }
    } else {
        int  xoff[3];
        bool xm[3];
#pragma unroll
        for (int j = 0; j < 3; ++j) {
            const int xx = col + (j * 2 - 2);
            xm[j]   = ((unsigned)xx < (unsigned)WW);
            xoff[j] = xx & (WW - 1);
        }
#pragma unroll 1
        for (int cti = 0; cti < 2; ++cti) {
            const int cb = z * 32 + cti * 16 + crow;
            const float* xc = xb + (size_t)cb * HWSZ;
            f32x4 acc = {0.f, 0.f, 0.f, 0.f};
#pragma unroll
            for (int k = 0; k < K2; ++k) {
                const int yy  = y + ((k / 3) * 2 - 2);
                const int off = ((yy & (HH - 1)) << 7) + xoff[k % 3];
                const float m = (xm[k % 3] && ((unsigned)yy < (unsigned)HH)) ? 1.f : 0.f;
                const f16x8 af = afl[(cti * K2 + k) * 64 + lane];
                const f32x4 wg = __builtin_amdgcn_mfma_f32_16x16x32_f16(af, tnf, zc, 0, 0, 0);
                acc[0] = fmaf(wg[0], xc[off + 0 * HWSZ] * m, acc[0]);
                acc[1] = fmaf(wg[1], xc[off + 1 * HWSZ] * m, acc[1]);
                acc[2] = fmaf(wg[2], xc[off + 2 * HWSZ] * m, acc[2]);
                acc[3] = fmaf(wg[3], xc[off + 3 * HWSZ] * m, acc[3]);
            }
            float* o = ob + (size_t)cb * HWSZ + pix;
            o[0 * HWSZ] = acc[0];
            o[1 * HWSZ] = acc[1];
            o[2 * HWSZ] = acc[2];
            o[3 * HWSZ] = acc[3];
        }
    }
}

extern "C" void kernel_launch(void* const* d_in, const int* in_sizes, int n_in,
                              void* d_out, int out_size, void* d_ws, size_t ws_size,
                              hipStream_t stream) {
    const float* x     = (const float*)d_in[0];
    const float* w1    = (const float*)d_in[1];
    const float* gamma = (const float*)d_in[2];
    const float* beta  = (const float*)d_in[3];
    const float* w2    = (const float*)d_in[4];
    const float* b2    = (const float*)d_in[5];
    float* out = (float*)d_out;

    float* ws = (float*)d_ws;

    k_prep<<<18, 256, 0, stream>>>(w2, b2, ws);

    dim3 gA(64, 8);
    k_conv1<<<gA, 256, 0, stream>>>(x, w1, ws + WS_T, ws + WS_PART);

    k_stats<<<128, 64, 0, stream>>>(ws + WS_PART, gamma, beta, ws + WS_STATS);

    k_norm<<<512, 256, 0, stream>>>(ws + WS_T, ws + WS_STATS, (f16x8*)(ws + WS_TN16));

    k_main<<<8192, 256, 0, stream>>>(x, ws, out);
}

// Round 9
// 81.001 us; speedup vs baseline: 1.2633x; 1.2633x over previous
//
#include <hip/hip_runtime.h>

// Problem constants
#define BB   8
#define CC   128
#define CR   16      // reduced channels = 128/8
#define HH   128
#define WW   128
#define HWSZ 16384   // 128*128
#define K2   9
#define NFRAG 72     // 8 ctiles * 9 taps

typedef _Float16 f16x8 __attribute__((ext_vector_type(8)));
typedef float    f32x4 __attribute__((ext_vector_type(4)));

// ws layout (float slots):
//   t     : [0, 2097152)             (b, cr, h, w) fp32
//   part  : [2097152, +16384)
//   stats : [2113536, +256)          (b,cr) x {scale,shift}
//   tn16  : [2113792, +1048576)      normalized t, f16, (b, hw, 16) packed
//   afrag : [3162368, +18432)        A fragments f16x8/lane (bias folded at kk=16)
#define WS_T     0
#define WS_PART  2097152
#define WS_STATS 2113536
#define WS_TN16  2113792
#define WS_AFRAG 3162368

__global__ __launch_bounds__(256) void k_conv1(const float* __restrict__ x,
                                               const float* __restrict__ w1,
                                               float* __restrict__ t,
                                               float* __restrict__ part) {
    const int tile = blockIdx.x;   // 0..63
    const int b    = blockIdx.y;   // 0..7
    const int tid  = threadIdx.x;
    const int pix  = tile * 256 + tid;

    __shared__ float w1s[CR * CC];   // 8 KB
    for (int i = tid; i < CR * CC; i += 256) w1s[i] = w1[i];
    __syncthreads();

    const float* xb = x + (size_t)b * CC * HWSZ + pix;
    float acc[CR];
#pragma unroll
    for (int o = 0; o < CR; ++o) acc[o] = 0.f;

    for (int cin = 0; cin < CC; ++cin) {
        float xv = xb[(size_t)cin * HWSZ];
#pragma unroll
        for (int o = 0; o < CR; ++o)
            acc[o] = fmaf(w1s[o * CC + cin], xv, acc[o]);
    }

    float* tb = t + (size_t)b * CR * HWSZ + pix;
#pragma unroll
    for (int o = 0; o < CR; ++o) tb[(size_t)o * HWSZ] = acc[o];

    __shared__ float red[4][CR][2];
    const int lane = tid & 63;
    const int wv   = tid >> 6;
#pragma unroll
    for (int o = 0; o < CR; ++o) {
        float s = acc[o];
        float q = s * s;
#pragma unroll
        for (int off = 32; off > 0; off >>= 1) {
            s += __shfl_down(s, off, 64);
            q += __shfl_down(q, off, 64);
        }
        if (lane == 0) { red[wv][o][0] = s; red[wv][o][1] = q; }
    }
    __syncthreads();
    if (tid < CR) {
        const int o = tid;
        float s = red[0][o][0] + red[1][o][0] + red[2][o][0] + red[3][o][0];
        float q = red[0][o][1] + red[1][o][1] + red[2][o][1] + red[3][o][1];
        const int blk = b * 64 + tile;
        part[blk * 32 + o * 2 + 0] = s;
        part[blk * 32 + o * 2 + 1] = q;
    }
}

// grid = 128 blocks (b*16+o), block = 64; wave-reduce over 64 tiles
__global__ void k_stats(const float* __restrict__ part,
                        const float* __restrict__ gamma,
                        const float* __restrict__ beta,
                        float* __restrict__ stats) {
    const int b   = blockIdx.x >> 4;
    const int o   = blockIdx.x & 15;
    const int tle = threadIdx.x;            // 0..63
    float s = part[(b * 64 + tle) * 32 + o * 2 + 0];
    float q = part[(b * 64 + tle) * 32 + o * 2 + 1];
#pragma unroll
    for (int off = 32; off > 0; off >>= 1) {
        s += __shfl_down(s, off, 64);
        q += __shfl_down(q, off, 64);
    }
    if (tle == 0) {
        const float mean = s * (1.f / (float)HWSZ);
        const float var  = q * (1.f / (float)HWSZ) - mean * mean;
        const float rstd = rsqrtf(var + 1e-5f);
        const float sc   = gamma[o] * rstd;
        const float sh   = beta[o] - mean * sc;
        stats[(b * CR + o) * 2 + 0] = sc;
        stats[(b * CR + o) * 2 + 1] = sh;
    }
}

// Normalize t -> packed f16 (b, hw, 16); one thread per pixel.
__global__ __launch_bounds__(256) void k_norm(const float* __restrict__ ws_t,
                                              const float* __restrict__ stats,
                                              f16x8* __restrict__ tn16) {
    const int p  = blockIdx.x * 256 + threadIdx.x;   // 0..131071
    const int b  = p >> 14;
    const int pp = p & 16383;
    const float* tb = ws_t + (size_t)b * CR * HWSZ + pp;
    const float* st = stats + b * CR * 2;
    f16x8 lo, hi;
#pragma unroll
    for (int i = 0; i < 8; ++i) {
        float v0 = fmaf(tb[(size_t)i * HWSZ],       st[i * 2],       st[i * 2 + 1]);
        float v1 = fmaf(tb[(size_t)(i + 8) * HWSZ], st[(i + 8) * 2], st[(i + 8) * 2 + 1]);
        lo[i] = (_Float16)(v0 > 0.f ? v0 : 0.f);
        hi[i] = (_Float16)(v1 > 0.f ? v1 : 0.f);
    }
    tn16[(size_t)p * 2 + 0] = lo;
    tn16[(size_t)p * 2 + 1] = hi;
}

// Pre-swizzle w2 into MFMA A-fragments (f16), bias folded at kk==16.
// A-frag (16x16x32_f16): lane holds A[row=lane&15][kk=8*(lane>>4)+i].
__global__ __launch_bounds__(256) void k_prep(const float* __restrict__ w2,
                                              const float* __restrict__ b2,
                                              float* __restrict__ ws) {
    const int id = blockIdx.x * 256 + threadIdx.x;
    if (id >= NFRAG * 64) return;
    const int lane = id & 63;
    const int frag = id >> 6;           // ct*9 + k
    const int ct = frag / 9, k = frag - ct * 9;
    const int row = lane & 15, lg = lane >> 4;
    f16x8 v;
#pragma unroll
    for (int i = 0; i < 8; ++i) {
        const int kk = lg * 8 + i;
        float w = 0.f;
        if (kk < CR)        w = w2[(size_t)((ct * 16 + row) * K2 + k) * CR + kk];
        else if (kk == CR)  w = b2[(ct * 16 + row) * K2 + k];
        v[i] = (_Float16)w;
    }
    f16x8* dst = (f16x8*)(ws + WS_AFRAG);
    dst[frag * 64 + lane] = v;
}

// Fused MFMA weight-gen + dilated 3x3 involution apply.
// NO LDS, NO barriers: each WAVE owns (b, ctile, y, xhalf) and keeps its
// 9 A-fragments in registers (36 VGPR), sweeping 4 x-groups of 16 px.
// Block = 4 independent waves at adjacent y (tap rows share L1/L2).
// grid = 4096, XCD-chunked swizzle, y innermost for L2 tap locality.
__global__ __launch_bounds__(256) void k_main(const float* __restrict__ x,
                                              const float* __restrict__ ws,
                                              float* __restrict__ out) {
    const int bid = blockIdx.x;                 // 0..4095
    const int w   = (bid & 7) * 512 + (bid >> 3);
    const int y4    = w & 31;
    const int xhalf = (w >> 5) & 1;
    const int ct    = (w >> 6) & 7;
    const int b     = w >> 9;

    const int tid  = threadIdx.x;
    const int wv   = tid >> 6;
    const int lane = tid & 63;
    const int lg   = lane >> 4;           // 0..3
    const int ln   = lane & 15;
    const int y    = y4 * 4 + wv;

    // ---- 9 A-fragments into registers (L2-hot ws reads, once per wave) ----
    const f16x8* afr = (const f16x8*)(ws + WS_AFRAG) + (size_t)ct * K2 * 64 + lane;
    f16x8 af[K2];
#pragma unroll
    for (int k = 0; k < K2; ++k) af[k] = afr[k * 64];

    const int crow = lg * 4;
    const int cb   = ct * 16 + crow;
    const float* xp = x   + ((size_t)b * CC + cb) * HWSZ;
    float*       op = out + ((size_t)b * CC + cb) * HWSZ;
    const f16x8* tns = (const f16x8*)(ws + WS_TN16) + ((size_t)b << 15);
    const bool yint = (y >= 2) && (y < HH - 2);
    const f32x4 zc = {0.f, 0.f, 0.f, 0.f};

#pragma unroll 1
    for (int g = 0; g < 4; ++g) {
        const int colb = xhalf * 64 + g * 16;
        const int col  = colb + ln;
        const int pix  = y * WW + col;

        // B-fragment: one 16B load of packed normalized t (bias lane kk==16 -> 1)
        f16x8 tnf = {};
        if (lg < 2) {
            tnf = tns[(size_t)pix * 2 + lg];
        } else if (lg == 2) {
            tnf[0] = (_Float16)1.f;
        }

        f32x4 acc = {0.f, 0.f, 0.f, 0.f};
        const bool xint = (colb >= 2) && (colb + 17 < WW);

        if (yint && xint) {
            const float* q0 = xp + pix;
            const float* q1 = q0 + HWSZ;
            const float* q2 = q0 + 2 * HWSZ;
            const float* q3 = q0 + 3 * HWSZ;
#pragma unroll
            for (int k = 0; k < K2; ++k) {
                const int d = ((k / 3) * 2 - 2) * WW + ((k % 3) * 2 - 2);  // compile-time imm
                const f32x4 wg = __builtin_amdgcn_mfma_f32_16x16x32_f16(af[k], tnf, zc, 0, 0, 0);
                acc[0] = fmaf(wg[0], q0[d], acc[0]);
                acc[1] = fmaf(wg[1], q1[d], acc[1]);
                acc[2] = fmaf(wg[2], q2[d], acc[2]);
                acc[3] = fmaf(wg[3], q3[d], acc[3]);
            }
        } else {
            int  xoff[3];
            bool xm[3];
#pragma unroll
            for (int j = 0; j < 3; ++j) {
                const int xx = col + (j * 2 - 2);
                xm[j]   = ((unsigned)xx < (unsigned)WW);
                xoff[j] = xx & (WW - 1);
            }
#pragma unroll
            for (int k = 0; k < K2; ++k) {
                const int yy  = y + ((k / 3) * 2 - 2);
                const int off = ((yy & (HH - 1)) << 7) + xoff[k % 3];
                const float m = (xm[k % 3] && ((unsigned)yy < (unsigned)HH)) ? 1.f : 0.f;
                const f32x4 wg = __builtin_amdgcn_mfma_f32_16x16x32_f16(af[k], tnf, zc, 0, 0, 0);
                acc[0] = fmaf(wg[0], xp[off + 0 * HWSZ] * m, acc[0]);
                acc[1] = fmaf(wg[1], xp[off + 1 * HWSZ] * m, acc[1]);
                acc[2] = fmaf(wg[2], xp[off + 2 * HWSZ] * m, acc[2]);
                acc[3] = fmaf(wg[3], xp[off + 3 * HWSZ] * m, acc[3]);
            }
        }

        float* o = op + pix;
        o[0 * HWSZ] = acc[0];
        o[1 * HWSZ] = acc[1];
        o[2 * HWSZ] = acc[2];
        o[3 * HWSZ] = acc[3];
    }
}

extern "C" void kernel_launch(void* const* d_in, const int* in_sizes, int n_in,
                              void* d_out, int out_size, void* d_ws, size_t ws_size,
                              hipStream_t stream) {
    const float* x     = (const float*)d_in[0];
    const float* w1    = (const float*)d_in[1];
    const float* gamma = (const float*)d_in[2];
    const float* beta  = (const float*)d_in[3];
    const float* w2    = (const float*)d_in[4];
    const float* b2    = (const float*)d_in[5];
    float* out = (float*)d_out;

    float* ws = (float*)d_ws;

    k_prep<<<18, 256, 0, stream>>>(w2, b2, ws);

    dim3 gA(64, 8);
    k_conv1<<<gA, 256, 0, stream>>>(x, w1, ws + WS_T, ws + WS_PART);

    k_stats<<<128, 64, 0, stream>>>(ws + WS_PART, gamma, beta, ws + WS_STATS);

    k_norm<<<512, 256, 0, stream>>>(ws + WS_T, ws + WS_STATS, (f16x8*)(ws + WS_TN16));

    k_main<<<4096, 256, 0, stream>>>(x, ws, out);
}